// Round 3
// baseline (2754.916 us; speedup 1.0000x reference)
//
#include <hip/hip_runtime.h>
#include <stdint.h>

#define BB 8
#define NN 65536
#define GG 512
#define MM 64
#define STEPS 63            // GROUP_SIZE - 1
#define NWALK (BB*GG)       // 4096

#define FPK 64              // FPS blocks per batch
#define FPT 64              // threads per FPS block = 1 wave
#define PPT (NN/(FPK*FPT))  // 16 points per thread
#define FPS_BLOCKS (BB*FPK) // 512
#define WALK_BLOCKS (NWALK/64) // 64

// ---------------- threefry2x32 (JAX-exact, 20 rounds) ----------------
__device__ __forceinline__ uint32_t rotl32(uint32_t x, uint32_t r){ return (x<<r)|(x>>(32u-r)); }

__device__ __forceinline__ void tf2x32(uint32_t k0, uint32_t k1, uint32_t x0, uint32_t x1,
                                       uint32_t &o0, uint32_t &o1){
  const uint32_t ks2 = k0 ^ k1 ^ 0x1BD11BDAu;
  x0 += k0; x1 += k1;
#define TFR(r) { x0 += x1; x1 = rotl32(x1,(r)); x1 ^= x0; }
  TFR(13) TFR(15) TFR(26) TFR(6)
  x0 += k1;  x1 += ks2 + 1u;
  TFR(17) TFR(29) TFR(16) TFR(24)
  x0 += ks2; x1 += k0 + 2u;
  TFR(13) TFR(15) TFR(26) TFR(6)
  x0 += k0;  x1 += k1 + 3u;
  TFR(17) TFR(29) TFR(16) TFR(24)
  x0 += k1;  x1 += ks2 + 4u;
  TFR(13) TFR(15) TFR(26) TFR(6)
  x0 += ks2; x1 += k0 + 5u;
#undef TFR
  o0 = x0; o1 = x1;
}

// ---------------- kernel A: PRNG table + slot/center zeroing ----------------
__global__ void rng_init_kernel(uint4* __restrict__ rng,
                                unsigned long long* __restrict__ slots,
                                int* __restrict__ center_idx){
  int tid = blockIdx.x*blockDim.x + threadIdx.x;
  if (tid < 2*BB*FPK) slots[tid] = 0ull;          // ping-pong tagged slots (tag 0 = idle)
  if (tid < NWALK) center_idx[tid] = 0;           // 0 = "not ready" (winner idx is never 0 for it>=1)
  if (tid >= STEPS*NWALK) return;
  int step = tid / NWALK;
  int walk = tid - step*NWALK;
  uint32_t kj0,kj1,t0,t1,a0,a1,b0,b1,p0,p1,q0,q1,r0,r1,l0,l1;
  tf2x32(0u, 42u, 0u, (uint32_t)walk, kj0, kj1);  // key_j = TF(master(0,42), (0,j))
  tf2x32(kj0, kj1, 0u, (uint32_t)step, t0, t1);   // step key
  tf2x32(t0, t1, 0u, 0u, a0, a1);                 // ka
  tf2x32(t0, t1, 0u, 1u, b0, b1);                 // kb
  tf2x32(a0, a1, 0u, 0u, p0, p1);                 // uniform bits x3
  tf2x32(a0, a1, 0u, 1u, q0, q1);
  tf2x32(a0, a1, 0u, 2u, r0, r1);
  tf2x32(b0, b1, 0u, 1u, l0, l1);                 // randint lower bits
  uint4 e;
  e.x = ((p0 ^ p1) >> 9) | 0x3f800000u;
  e.y = ((q0 ^ q1) >> 9) | 0x3f800000u;
  e.z = ((r0 ^ r1) >> 9) | 0x3f800000u;
  e.w = (l0 ^ l1) & 0xFFFFu;
  rng[tid] = e;
}

// ---------------- kernel B: fused FPS + random walks ----------------
// Blocks 0..511: FPS, 1 wave each, 64 blocks/batch, 16 pts/thread in registers.
//   Slot value = dist_bits<<32 | (65535-idx)<<16 | it_tag. Ping-pong [2][BB][FPK];
//   WAR across iterations is impossible by the handshake order (a block reaches
//   it+2 only after all peers finished reading it). Lane j polls slot j ->
//   one coalesced 512B load per poll round; candidate coords prefetched per
//   lane during straggler wait, winner's coords shfl-broadcast.
// Blocks 512..575: walks, 1 walk/thread; spin on center_idx (published
//   progressively by FPS) then serial 63 steps touching only ring+rng+LDS hash.
__global__ __launch_bounds__(64) void fps_walk_kernel(const float* __restrict__ xyz,
                                                      const int* __restrict__ ring,
                                                      const uint4* __restrict__ rng,
                                                      unsigned long long* __restrict__ slots,
                                                      int* __restrict__ center_idx,
                                                      float* __restrict__ out){
  const int t = threadIdx.x;
  if (blockIdx.x < FPS_BLOCKS){
    const int b = blockIdx.x & 7;
    const int k = blockIdx.x >> 3;
    const float* bx = xyz + (size_t)b*NN*3;
    float px[PPT], py[PPT], pz[PPT], dd[PPT];
    const int base = k*(FPT*PPT);
#pragma unroll
    for(int q=0;q<PPT;q++){
      int gi = base + q*FPT + t;
      px[q]=bx[3*gi]; py[q]=bx[3*gi+1]; pz[q]=bx[3*gi+2];
      dd[q]=1e10f;
    }
    float cx = bx[0], cy = bx[1], cz = bx[2];     // start center = index 0
    for(int it=1; it<GG; ++it){
      unsigned long long best = 0ull;
#pragma unroll
      for(int q=0;q<PPT;q++){
        // match XLA: uncontracted mul/add, sum order ((dx^2+dy^2)+dz^2)
        float dx = __fadd_rn(px[q], -cx);
        float dy = __fadd_rn(py[q], -cy);
        float dz = __fadd_rn(pz[q], -cz);
        float d  = __fmul_rn(dx,dx);
        d = __fadd_rn(d, __fmul_rn(dy,dy));
        d = __fadd_rn(d, __fmul_rn(dz,dz));
        float nd = fminf(dd[q], d);
        dd[q] = nd;
        int gi = base + q*FPT + t;
        unsigned long long key = ((unsigned long long)__float_as_uint(nd) << 32)
                               | ((unsigned long long)(unsigned)(65535 - gi) << 16);
        best = key > best ? key : best;
      }
#pragma unroll
      for(int off=32; off; off>>=1){
        unsigned long long o = __shfl_xor(best, off, 64);
        best = o > best ? o : best;               // block best in every lane
      }
      unsigned long long* sl = slots + (((size_t)(it & 1))*BB + b)*FPK;
      if (t==0)
        __hip_atomic_store(&sl[k], best | (unsigned)it, __ATOMIC_RELAXED, __HIP_MEMORY_SCOPE_AGENT);
      // lane j polls slot j (coalesced across the wave)
      unsigned long long v;
      do { v = __hip_atomic_load(&sl[t], __ATOMIC_RELAXED, __HIP_MEMORY_SCOPE_AGENT); }
      while ((v & 0xFFFFull) != (unsigned long long)it);
      // prefetch candidate coords while stragglers arrive
      unsigned int idxj = 65535u - (unsigned)((v >> 16) & 0xFFFFu);
      float pcx = bx[3*idxj], pcy = bx[3*idxj+1], pcz = bx[3*idxj+2];
      unsigned long long m = v;
#pragma unroll
      for(int off=32; off; off>>=1){
        unsigned long long o = __shfl_xor(m, off, 64);
        m = o > m ? o : m;                        // global max (tags equal -> compares dist,idx)
      }
      unsigned long long bal = __ballot(v == m);  // winner slot is unique (disjoint shards)
      int wl = __ffsll((unsigned long long)bal) - 1;
      cx = __shfl(pcx, wl, 64);
      cy = __shfl(pcy, wl, 64);
      cz = __shfl(pcz, wl, 64);
      if (t==0 && k==0){
        int widx = (int)(65535u - (unsigned)((m >> 16) & 0xFFFFu));
        __hip_atomic_store(&center_idx[b*GG + it], widx, __ATOMIC_RELAXED, __HIP_MEMORY_SCOPE_AGENT);
      }
    }
  } else {
    // ---------------- walk part ----------------
    __shared__ uint32_t hashv[128*64];            // [slot][thread], 32 KiB, private columns
    for(int i=0;i<128;i++) hashv[i*64 + t] = 0u;
    const int walk = (blockIdx.x - FPS_BLOCKS)*64 + t;
    const int b = walk >> 9;
    const int g = walk & 511;
    const int* br = ring + (size_t)b*NN*3;
    float* out_i = out + (size_t)NWALK*MM*3 + (size_t)NWALK*3;   // [NWALK][64] as float

    int cidx = 0;
    if (g){
      do {
        cidx = __hip_atomic_load(&center_idx[walk], __ATOMIC_RELAXED, __HIP_MEMORY_SCOPE_AGENT);
        if (cidx) break;
        __builtin_amdgcn_s_sleep(4);
      } while (true);
    }
    auto ins = [&](uint32_t v){
      uint32_t h = (v*2654435761u) >> 25;
      for(;;){ uint32_t c = hashv[h*64+t];
               if (c==v+1u) return;
               if (c==0u){ hashv[h*64+t]=v+1u; return; }
               h=(h+1u)&127u; }
    };
    auto has = [&](uint32_t v)->bool{
      uint32_t h = (v*2654435761u) >> 25;
      for(;;){ uint32_t c = hashv[h*64+t];
               if (c==0u) return false;
               if (c==v+1u) return true;
               h=(h+1u)&127u; }
    };
    ins((uint32_t)cidx);
    out_i[(size_t)walk*MM] = (float)cidx;
    int cur = cidx;
    uint4 e = rng[walk];                          // step 0 entry
    for(int i=0;i<STEPS;i++){
      uint4 en = (i < STEPS-1) ? rng[(size_t)(i+1)*NWALK + walk] : e;  // prefetch next
      int n0 = br[3*cur], n1 = br[3*cur+1], n2 = br[3*cur+2];
      bool m0 = !has((uint32_t)n0), m1 = !has((uint32_t)n1), m2 = !has((uint32_t)n2);
      float s0 = m0 ? __fadd_rn(__uint_as_float(e.x), -1.0f) : -1.0f;
      float s1 = m1 ? __fadd_rn(__uint_as_float(e.y), -1.0f) : -1.0f;
      float s2 = m2 ? __fadd_rn(__uint_as_float(e.z), -1.0f) : -1.0f;
      int pick = n0; float sb = s0;               // first-max-wins argmax
      if (s1 > sb){ sb=s1; pick=n1; }
      if (s2 > sb){ sb=s2; pick=n2; }
      int nxt = (m0||m1||m2) ? pick : (int)e.w;
      ins((uint32_t)nxt);
      out_i[(size_t)walk*MM + i+1] = (float)nxt;
      cur = nxt; e = en;
    }
  }
}

// ---------------- kernel C: parallel gather epilogue ----------------
// One thread per (walk, j): neighborhood = xyz[idx] - xyz[cidx]; also out_c.
__global__ __launch_bounds__(256) void gather_kernel(const float* __restrict__ xyz,
                                                     float* __restrict__ out){
  const int tid = blockIdx.x*256 + threadIdx.x;   // 0 .. NWALK*MM-1
  const int walk = tid >> 6;
  const int j = tid & 63;
  const int b = walk >> 9;
  const float* bx = xyz + (size_t)b*NN*3;
  const float* oi = out + (size_t)NWALK*MM*3 + (size_t)NWALK*3;
  const int cidx = (int)oi[(size_t)walk*MM];
  const int idx  = (int)oi[tid];
  float cxv = bx[3*cidx], cyv = bx[3*cidx+1], czv = bx[3*cidx+2];
  float vx = __fadd_rn(bx[3*idx],   -cxv);
  float vy = __fadd_rn(bx[3*idx+1], -cyv);
  float vz = __fadd_rn(bx[3*idx+2], -czv);
  size_t o = (size_t)tid*3;
  out[o] = vx; out[o+1] = vy; out[o+2] = vz;
  if (j==0){
    float* oc = out + (size_t)NWALK*MM*3;
    oc[walk*3+0]=cxv; oc[walk*3+1]=cyv; oc[walk*3+2]=czv;
  }
}

// ---------------- launcher ----------------
extern "C" void kernel_launch(void* const* d_in, const int* in_sizes, int n_in,
                              void* d_out, int out_size, void* d_ws, size_t ws_size,
                              hipStream_t stream) {
  const float* xyz  = (const float*)d_in[0];
  const int*   ring = (const int*)d_in[1];

  // workspace layout
  unsigned long long* slots = (unsigned long long*)d_ws;            // 2*8*64*8 = 8192 B
  int*   center_idx = (int*)((char*)d_ws + 8192);                   // 4096*4 = 16384 B
  uint4* rng        = (uint4*)((char*)d_ws + 8192 + 16384);         // 258048*16 B
  float* out        = (float*)d_out;

  hipLaunchKernelGGL(rng_init_kernel, dim3((STEPS*NWALK)/256), dim3(256), 0, stream,
                     rng, slots, center_idx);
  hipLaunchKernelGGL(fps_walk_kernel, dim3(FPS_BLOCKS + WALK_BLOCKS), dim3(64), 0, stream,
                     xyz, ring, rng, slots, center_idx, out);
  hipLaunchKernelGGL(gather_kernel, dim3((NWALK*MM)/256), dim3(256), 0, stream,
                     xyz, out);
}

// Round 4
// 1539.981 us; speedup vs baseline: 1.7889x; 1.7889x over previous
//
#include <hip/hip_runtime.h>
#include <stdint.h>

#define BB 8
#define NN 65536
#define GG 512
#define MM 64
#define STEPS 63            // GROUP_SIZE - 1
#define NWALK (BB*GG)       // 4096

#define FPT 256             // threads per FPS block (4 waves)
#define FPK 32              // FPS blocks per batch
#define PPT (NN/(FPK*FPT))  // 8 points per thread
#define FPS_BLOCKS (BB*FPK) // 256

typedef unsigned long long ull;

// ---------------- threefry2x32 (JAX-exact, 20 rounds) ----------------
__device__ __forceinline__ uint32_t rotl32(uint32_t x, uint32_t r){ return (x<<r)|(x>>(32u-r)); }

__device__ __forceinline__ void tf2x32(uint32_t k0, uint32_t k1, uint32_t x0, uint32_t x1,
                                       uint32_t &o0, uint32_t &o1){
  const uint32_t ks2 = k0 ^ k1 ^ 0x1BD11BDAu;
  x0 += k0; x1 += k1;
#define TFR(r) { x0 += x1; x1 = rotl32(x1,(r)); x1 ^= x0; }
  TFR(13) TFR(15) TFR(26) TFR(6)
  x0 += k1;  x1 += ks2 + 1u;
  TFR(17) TFR(29) TFR(16) TFR(24)
  x0 += ks2; x1 += k0 + 2u;
  TFR(13) TFR(15) TFR(26) TFR(6)
  x0 += k0;  x1 += k1 + 3u;
  TFR(17) TFR(29) TFR(16) TFR(24)
  x0 += k1;  x1 += ks2 + 4u;
  TFR(13) TFR(15) TFR(26) TFR(6)
  x0 += ks2; x1 += k0 + 5u;
#undef TFR
  o0 = x0; o1 = x1;
}

// ---------------- kernel A: PRNG table + slot/center init ----------------
__global__ void rng_init_kernel(uint4* __restrict__ rng,
                                ull* __restrict__ slots,
                                int* __restrict__ center_idx){
  int tid = blockIdx.x*blockDim.x + threadIdx.x;
  if (tid < 2*BB*FPK) slots[tid] = 0ull;          // tagged ping-pong slots (tag 0 = idle)
  if (tid < BB) center_idx[tid*GG] = 0;           // FPS start index = 0
  if (tid >= STEPS*NWALK) return;
  int step = tid / NWALK;
  int walk = tid - step*NWALK;
  uint32_t kj0,kj1,t0,t1,a0,a1,b0,b1,p0,p1,q0,q1,r0,r1,l0,l1;
  tf2x32(0u, 42u, 0u, (uint32_t)walk, kj0, kj1);  // key_j = TF(master(0,42), (0,j))
  tf2x32(kj0, kj1, 0u, (uint32_t)step, t0, t1);   // step key
  tf2x32(t0, t1, 0u, 0u, a0, a1);                 // ka
  tf2x32(t0, t1, 0u, 1u, b0, b1);                 // kb
  tf2x32(a0, a1, 0u, 0u, p0, p1);                 // uniform bits x3
  tf2x32(a0, a1, 0u, 1u, q0, q1);
  tf2x32(a0, a1, 0u, 2u, r0, r1);
  tf2x32(b0, b1, 0u, 1u, l0, l1);                 // randint lower bits
  uint4 e;
  e.x = ((p0 ^ p1) >> 9) | 0x3f800000u;
  e.y = ((q0 ^ q1) >> 9) | 0x3f800000u;
  e.z = ((r0 ^ r1) >> 9) | 0x3f800000u;
  e.w = (l0 ^ l1) & 0xFFFFu;
  rng[tid] = e;
}

// ---------------- kernel B: farthest point sampling ----------------
// 8 batches x 32 blocks x 256 threads (4 waves, ~1 block/CU); 8 pts/thread.
// Slot value = dist_bits<<32 | (65535-idx)<<16 | it_tag, ping-pong [2][BB][FPK]
// (WAR-safe: a block reaches it+2 only after all peers finished reading it).
// One polling wave per block; lane j polls slot j (one coalesced 256B load),
// prefetches its candidate's coords, winner coords shfl-broadcast.
__global__ __launch_bounds__(FPT) void fps_kernel(const float* __restrict__ xyz,
                                                  ull* __restrict__ slots,
                                                  int* __restrict__ center_idx){
  const int b = blockIdx.x & 7;     // batch (blocks of a batch share an XCD for xyz L2 locality)
  const int k = blockIdx.x >> 3;    // shard 0..31
  const int t = threadIdx.x;
  const int w = t >> 6;             // wave 0..3
  const float* bx = xyz + (size_t)b*NN*3;
  float px[PPT], py[PPT], pz[PPT], dd[PPT];
  const int base = k*(FPT*PPT);
#pragma unroll
  for(int q=0;q<PPT;q++){
    int gi = base + q*FPT + t;
    px[q]=bx[3*gi]; py[q]=bx[3*gi+1]; pz[q]=bx[3*gi+2];
    dd[q]=1e10f;
  }
  __shared__ ull lred[FPT/64];
  __shared__ unsigned int bcw;
  __shared__ float bcx, bcy, bcz;
  float cx = bx[0], cy = bx[1], cz = bx[2];       // start center = index 0
  for(int it=1; it<GG; ++it){
    // per-thread scan: float best + idx (ascending gi + strict '>' keeps lowest idx)
    float bd = -1.0f; int bgi = 0;
#pragma unroll
    for(int q=0;q<PPT;q++){
      // match XLA: uncontracted mul/add, sum order ((dx^2+dy^2)+dz^2)
      float dx = __fadd_rn(px[q], -cx);
      float dy = __fadd_rn(py[q], -cy);
      float dz = __fadd_rn(pz[q], -cz);
      float d  = __fmul_rn(dx,dx);
      d = __fadd_rn(d, __fmul_rn(dy,dy));
      d = __fadd_rn(d, __fmul_rn(dz,dz));
      float nd = fminf(dd[q], d);
      dd[q] = nd;
      int gi = base + q*FPT + t;
      if (nd > bd){ bd = nd; bgi = gi; }
    }
    ull best = ((ull)__float_as_uint(bd) << 32) | ((ull)(unsigned)(65535 - bgi) << 16);
#pragma unroll
    for(int off=32; off; off>>=1){
      ull o = __shfl_xor(best, off, 64);
      best = o > best ? o : best;                 // wave max
    }
    if ((t & 63)==0) lred[w] = best;
    __syncthreads();
    if (w==0){
      ull bb = lred[0];
#pragma unroll
      for(int j=1;j<FPT/64;j++){ ull o = lred[j]; bb = o>bb?o:bb; }   // block max (all lanes)
      ull* sl = slots + (((size_t)(it & 1))*BB + b)*FPK;
      if (t==0)
        __hip_atomic_store(&sl[k], bb | (unsigned)it, __ATOMIC_RELAXED, __HIP_MEMORY_SCOPE_AGENT);
      // lane j polls slot j (coalesced 256B across lanes 0..31)
      ull v = 0; float pcx=0.f, pcy=0.f, pcz=0.f;
      if (t < FPK){
        do { v = __hip_atomic_load(&sl[t], __ATOMIC_RELAXED, __HIP_MEMORY_SCOPE_AGENT); }
        while ((v & 0xFFFFull) != (ull)(unsigned)it);
        unsigned int idxj = 65535u - (unsigned)((v >> 16) & 0xFFFFu);
        pcx = bx[3*idxj]; pcy = bx[3*idxj+1]; pcz = bx[3*idxj+2];   // prefetch during straggler wait
      }
      ull m = v;
#pragma unroll
      for(int off=16; off; off>>=1){
        ull o = __shfl_xor(m, off, 64);
        m = o > m ? o : m;                        // max over 32 slots (lanes 0..31 consistent)
      }
      ull bal = __ballot((t < FPK) && (v == m)); // winner slot unique (disjoint shards)
      int wl = (int)(__ffsll(bal) - 1);
      float wcx = __shfl(pcx, wl, 64);
      float wcy = __shfl(pcy, wl, 64);
      float wcz = __shfl(pcz, wl, 64);
      if (t==0){
        unsigned int widx = 65535u - (unsigned)((m >> 16) & 0xFFFFu);
        bcw = widx; bcx = wcx; bcy = wcy; bcz = wcz;
        if (k==0) center_idx[b*GG + it] = (int)widx;
      }
    }
    __syncthreads();
    cx = bcx; cy = bcy; cz = bcz;
  }
}

// ---------------- kernel C: random walks + gather, software-pipelined ----------------
// One thread per walk. Chain per step = hash probes + pick + row select;
// ring rows of all 3 candidates prefetched one step ahead (off-chain).
#define WBLK 64
__global__ __launch_bounds__(WBLK) void walk_kernel(const float* __restrict__ xyz,
                                                    const int* __restrict__ ring,
                                                    const uint4* __restrict__ rng,
                                                    const int* __restrict__ center_idx,
                                                    float* __restrict__ out){
  __shared__ uint32_t hashv[128*WBLK];            // [slot][thread], private columns (conflict-free)
  const int t = threadIdx.x;
  for(int i=0;i<128;i++) hashv[i*WBLK + t] = 0u;

  const int walk = blockIdx.x*WBLK + t;
  const int b = walk >> 9;
  const float* bx = xyz + (size_t)b*NN*3;
  const int*  br = ring + (size_t)b*NN*3;

  float* out_nb = out;                            // [NWALK][64][3]
  float* out_c  = out + (size_t)NWALK*MM*3;       // [NWALK][3]
  float* out_i  = out_c + (size_t)NWALK*3;        // [NWALK][64] (idx as float)

  const int cidx = center_idx[walk];
  const float cx = bx[3*cidx], cy = bx[3*cidx+1], cz = bx[3*cidx+2];
  out_c[walk*3+0]=cx; out_c[walk*3+1]=cy; out_c[walk*3+2]=cz;
  out_i[(size_t)walk*MM] = (float)cidx;
  { size_t o = (size_t)walk*MM*3; out_nb[o]=0.0f; out_nb[o+1]=0.0f; out_nb[o+2]=0.0f; }

  auto H = [](uint32_t v)->uint32_t { return (v*2654435761u) >> 25; };
  auto slow_has = [&](uint32_t v, uint32_t h)->bool{      // h = first probe slot (already checked)
    for(;;){ h=(h+1u)&127u; uint32_t c = hashv[h*WBLK+t];
             if (c==0u) return false;
             if (c==v+1u) return true; }
  };
  auto ins = [&](uint32_t v){
    uint32_t h = H(v);
    for(;;){ uint32_t c = hashv[h*WBLK+t];
             if (c==v+1u) return;
             if (c==0u){ hashv[h*WBLK+t]=v+1u; return; }
             h=(h+1u)&127u; }
  };

  ins((uint32_t)cidx);
  // initial candidates = ring row of the center, then prefetch their rows
  int n0 = br[3*cidx], n1 = br[3*cidx+1], n2 = br[3*cidx+2];
  int r00=br[3*n0], r01=br[3*n0+1], r02=br[3*n0+2];
  int r10=br[3*n1], r11=br[3*n1+1], r12=br[3*n1+2];
  int r20=br[3*n2], r21=br[3*n2+1], r22=br[3*n2+2];
  uint4 e = rng[walk];

  for(int i=0;i<STEPS;i++){
    uint4 en = (i < STEPS-1) ? rng[(size_t)(i+1)*NWALK + walk] : e;  // prefetch next rng
    // ILP'd first probes for the 3 candidates
    uint32_t h0=H((uint32_t)n0), h1=H((uint32_t)n1), h2=H((uint32_t)n2);
    uint32_t c0=hashv[h0*WBLK+t], c1=hashv[h1*WBLK+t], c2=hashv[h2*WBLK+t];
    bool v0 = (c0!=0u) && ((c0==(uint32_t)n0+1u) || slow_has((uint32_t)n0,h0));
    bool v1 = (c1!=0u) && ((c1==(uint32_t)n1+1u) || slow_has((uint32_t)n1,h1));
    bool v2 = (c2!=0u) && ((c2==(uint32_t)n2+1u) || slow_has((uint32_t)n2,h2));
    bool m0=!v0, m1=!v1, m2=!v2;
    float s0 = m0 ? __fadd_rn(__uint_as_float(e.x), -1.0f) : -1.0f;
    float s1 = m1 ? __fadd_rn(__uint_as_float(e.y), -1.0f) : -1.0f;
    float s2 = m2 ? __fadd_rn(__uint_as_float(e.z), -1.0f) : -1.0f;
    int s = 0; float sb = s0;                     // first-max-wins argmax slot
    if (s1 > sb){ sb=s1; s=1; }
    if (s2 > sb){ sb=s2; s=2; }
    bool any = m0|m1|m2;
    int pick = s==0 ? n0 : (s==1 ? n1 : n2);
    int nxt  = any ? pick : (int)e.w;
    // insert nxt (fast path reuses the picked candidate's first probe)
    if (any){
      uint32_t cs = s==0?c0:(s==1?c1:c2);
      uint32_t hs = s==0?h0:(s==1?h1:h2);
      if (cs==0u) hashv[hs*WBLK+t] = (uint32_t)nxt + 1u;
      else ins((uint32_t)nxt);                    // collision chain (rare)
    } else {
      ins((uint32_t)nxt);                         // random jump (rare)
    }
    out_i[(size_t)walk*MM + i+1] = (float)nxt;
    // gather + neighborhood store (off the serial chain)
    float gx=bx[3*nxt], gy=bx[3*nxt+1], gz=bx[3*nxt+2];
    // select next candidate row from the prefetched rows
    int nn0, nn1, nn2;
    if (any){
      nn0 = s==0?r00:(s==1?r10:r20);
      nn1 = s==0?r01:(s==1?r11:r21);
      nn2 = s==0?r02:(s==1?r12:r22);
    } else {
      nn0 = br[3*nxt]; nn1 = br[3*nxt+1]; nn2 = br[3*nxt+2];   // rare stall
    }
    n0=nn0; n1=nn1; n2=nn2;
    // prefetch rows of the new candidates (used next iteration)
    r00=br[3*n0]; r01=br[3*n0+1]; r02=br[3*n0+2];
    r10=br[3*n1]; r11=br[3*n1+1]; r12=br[3*n1+2];
    r20=br[3*n2]; r21=br[3*n2+1]; r22=br[3*n2+2];
    size_t o = ((size_t)walk*MM + (size_t)(i+1))*3;
    out_nb[o]   = __fadd_rn(gx, -cx);
    out_nb[o+1] = __fadd_rn(gy, -cy);
    out_nb[o+2] = __fadd_rn(gz, -cz);
    e = en;
  }
}

// ---------------- launcher ----------------
extern "C" void kernel_launch(void* const* d_in, const int* in_sizes, int n_in,
                              void* d_out, int out_size, void* d_ws, size_t ws_size,
                              hipStream_t stream) {
  const float* xyz  = (const float*)d_in[0];
  const int*   ring = (const int*)d_in[1];

  // workspace layout
  ull*   slots      = (ull*)d_ws;                                 // 2*8*32*8 = 4096 B
  int*   center_idx = (int*)((char*)d_ws + 8192);                 // 4096*4 B
  uint4* rng        = (uint4*)((char*)d_ws + 8192 + 16384);       // 258048*16 B
  float* out        = (float*)d_out;

  hipLaunchKernelGGL(rng_init_kernel, dim3((STEPS*NWALK)/256), dim3(256), 0, stream,
                     rng, slots, center_idx);
  hipLaunchKernelGGL(fps_kernel, dim3(FPS_BLOCKS), dim3(FPT), 0, stream,
                     xyz, slots, center_idx);
  hipLaunchKernelGGL(walk_kernel, dim3(NWALK/WBLK), dim3(WBLK), 0, stream,
                     xyz, ring, rng, center_idx, out);
}